// Round 9
// baseline (3249.160 us; speedup 1.0000x reference)
//
#include <hip/hip_runtime.h>
#include <math.h>

// Conv1D(k=2,F=64,relu) -> LSTM1(H=100, relu cell, seq) -> LSTM2 (last) ->
// Dense(3) -> softmax.  B=128, T=2048, T'=2047.
//
// Round-9 = round-8 with the ds_swizzle pattern moved to a template arg
// (the builtin demands an integer-constant expression at the call site).
//
// Design recap (round-8 register-cap arithmetic):
// block >= 13 waves forces 4 waves/SIMD -> unified reg cap 128/wave
// regardless of __launch_bounds__.  Per-lane weights + ~25 working set must
// fit 128 or the allocator demotes weights to AGPRs and v_dot2 pays an
// accvgpr_read per use (rounds 5/6/7 all hit this).
//  * 8 lanes per hidden unit: gate-split-4 x K-split-2.  Lane = (unit u,
//    gate gt, K-half kh).  Weights/lane: L1 44 h2 + L2 52 h2 = 96 VGPRs.
//  * BOTH layers merged into the same lanes: phase A = LSTM1 step t,
//    phase B = LSTM2 step t.  800 unit-lanes + 64 conv lanes = 896 threads
//    (14 waves, 3.5 waves/SIMD).
//  * Gate-duplicated x reads are same-address LDS broadcasts (free, m136).
//  * Reduce: xor1 (K-half sum) -> per-gate activation -> xor2/xor4/xor6
//    gathers; gt==0 lanes hold (i,f,g,o) with NO selects; sub==0 writes h.
//  * ONE __syncthreads per step (between A-writes and B-reads; all other
//    orderings cross that barrier on the next iteration).
//  * Biases folded via constant-1.0 elements in the LDS x-vectors.

typedef _Float16 h2 __attribute__((ext_vector_type(2)));

#define BB 128
#define TT 2048
#define TP 2047
#define HH 100
#define G4 400
#define FF 64

#define S1 176   // X1 slot: [x(64); h1(100)@64; 1.0@164; pad->176]
#define S2 208   // X2 slot: [h1(100); h2(100)@100; 1.0@200; pad->208]

#define W44(X) X(0) X(1) X(2) X(3) X(4) X(5) X(6) X(7) X(8) X(9) X(10) \
  X(11) X(12) X(13) X(14) X(15) X(16) X(17) X(18) X(19) X(20) X(21) X(22) \
  X(23) X(24) X(25) X(26) X(27) X(28) X(29) X(30) X(31) X(32) X(33) X(34) \
  X(35) X(36) X(37) X(38) X(39) X(40) X(41) X(42) X(43)
#define W52(X) W44(X) X(44) X(45) X(46) X(47) X(48) X(49) X(50) X(51)

#define DP1(j) h2 wp##j;
#define DP2(j) h2 wc##j;

// L1 combined K-vector element kk of gate column c: [x W(64); h U(100); b@164; 0]
static __device__ __forceinline__ float ev1(const float* __restrict__ W,
                                            const float* __restrict__ U,
                                            const float* __restrict__ Bv,
                                            int c, int kk) {
    if (kk < FF)       return W[kk * G4 + c];
    if (kk < FF + HH)  return U[(kk - FF) * G4 + c];
    if (kk == FF + HH) return Bv[c];
    return 0.0f;
}
// L2: [h1 W(100); h2 U(100); b@200; 0]
static __device__ __forceinline__ float ev2(const float* __restrict__ W,
                                            const float* __restrict__ U,
                                            const float* __restrict__ Bv,
                                            int c, int kk) {
    if (kk < HH)       return W[kk * G4 + c];
    if (kk < 2 * HH)   return U[(kk - HH) * G4 + c];
    if (kk == 2 * HH)  return Bv[c];
    return 0.0f;
}

#define LD1(j) wp##j = h2{(_Float16)ev1(w1,u1,b1,col,kb1+2*(j)), \
                          (_Float16)ev1(w1,u1,b1,col,kb1+2*(j)+1)};
#define LD2(j) wc##j = h2{(_Float16)ev2(w2,u2,b2,col,kb2+2*(j)), \
                          (_Float16)ev2(w2,u2,b2,col,kb2+2*(j)+1)};

#define B2(f) __builtin_bit_cast(h2, f)
#define FD(w, x, acc) acc = __builtin_amdgcn_fdot2(w, x, acc, false)

#define DA(i, a, b, c, d) { const float4 v = vb1[i]; \
  FD(wp##a, B2(v.x), z0); FD(wp##b, B2(v.y), z1); \
  FD(wp##c, B2(v.z), z2); FD(wp##d, B2(v.w), z3); }
#define DB(i, a, b, c, d) { const float4 v = vb2[i]; \
  FD(wc##a, B2(v.x), z0); FD(wc##b, B2(v.y), z1); \
  FD(wc##c, B2(v.z), z2); FD(wc##d, B2(v.w), z3); }

template <int PAT>
static __device__ __forceinline__ float swz(float z) {
    return __builtin_bit_cast(float,
        __builtin_amdgcn_ds_swizzle(__builtin_bit_cast(int, z), PAT));
}
static __device__ __forceinline__ float sig(float z) {
    return 1.0f / (1.0f + __expf(-z));
}

__global__ __launch_bounds__(896, 4)
void fused_lstm_kernel(const float* __restrict__ inp,     // [B,T]
                       const float* __restrict__ conv_w,  // [2,1,F]
                       const float* __restrict__ conv_b,  // [F]
                       const float* __restrict__ w1, const float* __restrict__ u1,
                       const float* __restrict__ b1,
                       const float* __restrict__ w2, const float* __restrict__ u2,
                       const float* __restrict__ b2,
                       const float* __restrict__ dw, const float* __restrict__ db,
                       float* __restrict__ out)           // [B,3]
{
    const int tid = threadIdx.x;
    const int b   = blockIdx.x;

    __shared__ float s_buf[TT];
    __shared__ __align__(16) _Float16 X1[2 * S1];
    __shared__ __align__(16) _Float16 X2[2 * S2];

    for (int i = tid; i < TT; i += 896) s_buf[i] = inp[(size_t)b * TT + i];
    for (int i = tid; i < 2 * S1; i += 896) X1[i] = (_Float16)0.0f;
    for (int i = tid; i < 2 * S2; i += 896) X2[i] = (_Float16)0.0f;
    __syncthreads();
    if (tid == 0) {                                    // bias-input constants
        X1[FF + HH] = (_Float16)1.0f; X1[S1 + FF + HH] = (_Float16)1.0f;
        X2[2 * HH]  = (_Float16)1.0f; X2[S2 + 2 * HH]  = (_Float16)1.0f;
    }

    const bool unitlane = (tid < 800);
    const int u   = unitlane ? (tid >> 3) : 0;         // hidden unit
    const int sub = tid & 7;
    const int gt  = sub >> 1;                          // gate: 0=i 1=f 2=g 3=o
    const int kh  = sub & 1;                           // K-half
    const int col = gt * HH + u;                       // gate column in [0,4H)
    const int kb1 = kh * 88;                           // L1 K-half base
    const int kb2 = kh * 104;                          // L2 K-half base

    // ---- per-lane weights in named h2 registers (96 total) ----
    W44(DP1)
    W52(DP2)
    if (unitlane) { W44(LD1) W52(LD2) }

    // ---- conv lanes ----
    float cw0 = 0.f, cw1 = 0.f, cb0 = 0.f;
    const int f = tid - 800;
    if (tid >= 800 && tid < 864) {
        cw0 = conv_w[f]; cw1 = conv_w[FF + f]; cb0 = conv_b[f];
        // x(0) into X1 slot 0
        X1[f] = (_Float16)fmaxf(fmaf(s_buf[0], cw0, fmaf(s_buf[1], cw1, cb0)), 0.f);
    }
    __syncthreads();

    float c1 = 0.0f, c2 = 0.0f;
    for (int t = 0; t < TP; ++t) {
        const int cs = (t & 1), ns = cs ^ 1;
        // ================= phase A : LSTM1 step t =================
        if (unitlane) {
            float z0 = 0.f, z1 = 0.f, z2 = 0.f, z3 = 0.f;
            const float4* vb1 = (const float4*)(X1 + cs * S1 + kb1);
            DA(0,0,1,2,3)   DA(1,4,5,6,7)   DA(2,8,9,10,11)  DA(3,12,13,14,15)
            DA(4,16,17,18,19) DA(5,20,21,22,23) DA(6,24,25,26,27)
            DA(7,28,29,30,31) DA(8,32,33,34,35) DA(9,36,37,38,39)
            DA(10,40,41,42,43)
            float z = (z0 + z1) + (z2 + z3);
            z += swz<0x041F>(z);                       // K-half sum (xor1)
            const float a = (gt == 2) ? fmaxf(z, 0.f) : sig(z);
            const float af = swz<0x081F>(a);           // xor2
            const float ag = swz<0x101F>(a);           // xor4
            const float ao = swz<0x181F>(a);           // xor6
            // valid in gt==0 lanes: (a,af,ag,ao) = (i,f,g,o)
            c1 = fmaf(af, c1, a * ag);
            const float h = ao * fmaxf(c1, 0.f);
            if (sub == 0) {
                const _Float16 hq = (_Float16)h;
                X1[ns * S1 + FF + u] = hq;             // h1(t) for LSTM1(t+1)
                X2[cs * S2 + u]      = hq;             // h1(t) for LSTM2 phase B
            }
        } else if (tid < 864 && t + 1 < TP) {          // conv x(t+1) -> next slot
            X1[ns * S1 + f] = (_Float16)fmaxf(
                fmaf(s_buf[t + 1], cw0, fmaf(s_buf[t + 2], cw1, cb0)), 0.f);
        }
        __syncthreads();                               // the ONE barrier per step
        // ================= phase B : LSTM2 step t =================
        if (unitlane) {
            float z0 = 0.f, z1 = 0.f, z2 = 0.f, z3 = 0.f;
            const float4* vb2 = (const float4*)(X2 + cs * S2 + kb2);
            DB(0,0,1,2,3)   DB(1,4,5,6,7)   DB(2,8,9,10,11)  DB(3,12,13,14,15)
            DB(4,16,17,18,19) DB(5,20,21,22,23) DB(6,24,25,26,27)
            DB(7,28,29,30,31) DB(8,32,33,34,35) DB(9,36,37,38,39)
            DB(10,40,41,42,43) DB(11,44,45,46,47) DB(12,48,49,50,51)
            float z = (z0 + z1) + (z2 + z3);
            z += swz<0x041F>(z);
            const float a = (gt == 2) ? fmaxf(z, 0.f) : sig(z);
            const float af = swz<0x081F>(a);
            const float ag = swz<0x101F>(a);
            const float ao = swz<0x181F>(a);
            c2 = fmaf(af, c2, a * ag);
            const float h = ao * fmaxf(c2, 0.f);
            if (sub == 0)
                X2[ns * S2 + HH + u] = (_Float16)h;    // h2(t)
        }
        // no barrier here: B(t) writes are ordered vs B(t+1) reads by the
        // barrier inside iteration t+1; A(t+1) touches disjoint regions.
    }
    __syncthreads();

    // final h2(TP-1) lives in X2 slot (TP & 1) = 1, h2-part
    if (tid == 0) {
        float l[3];
#pragma unroll
        for (int a = 0; a < 3; ++a) {
            float acc = db[a];
            for (int j = 0; j < HH; ++j)
                acc = fmaf((float)X2[S2 + HH + j], dw[j * 3 + a], acc);
            l[a] = acc;
        }
        const float m = fmaxf(l[0], fmaxf(l[1], l[2]));
        const float e0 = __expf(l[0] - m), e1 = __expf(l[1] - m), e2 = __expf(l[2] - m);
        const float inv = 1.0f / (e0 + e1 + e2);
        out[b * 3 + 0] = e0 * inv;
        out[b * 3 + 1] = e1 * inv;
        out[b * 3 + 2] = e2 * inv;
    }
}

// ---------------- launch ----------------------------------------------------
extern "C" void kernel_launch(void* const* d_in, const int* in_sizes, int n_in,
                              void* d_out, int out_size, void* d_ws, size_t ws_size,
                              hipStream_t stream) {
    const float* s      = (const float*)d_in[0];
    const float* conv_w = (const float*)d_in[1];
    const float* conv_b = (const float*)d_in[2];
    const float* w1     = (const float*)d_in[3];
    const float* u1     = (const float*)d_in[4];
    const float* b1     = (const float*)d_in[5];
    const float* w2     = (const float*)d_in[6];
    const float* u2     = (const float*)d_in[7];
    const float* b2     = (const float*)d_in[8];
    const float* dw     = (const float*)d_in[9];
    const float* db     = (const float*)d_in[10];

    fused_lstm_kernel<<<BB, 896, 0, stream>>>(
        s, conv_w, conv_b, w1, u1, b1, w2, u2, b2, dw, db, (float*)d_out);
}

// Round 10
// 2829.126 us; speedup vs baseline: 1.1485x; 1.1485x over previous
//
#include <hip/hip_runtime.h>
#include <math.h>

// Conv1D(k=2,F=64,relu) -> LSTM1(H=100, relu cell, seq) -> LSTM2 (last) ->
// Dense(3) -> softmax.  B=128, T=2048, T'=2047.
//
// Round-10.  Register law learned from rounds 4-9: the arch-VGPR cap comes
// from the block size (flat workgroup size): 1024/896-thr blocks -> 128
// unified regs/wave and the RA spills loop-invariant weights to AGPRs
// (VGPR_Count=64, accvgpr_read per weight per step).  256-thr block got 228
// arch regs.  So: 512 threads, __launch_bounds__(512,1) -> cap 256, and the
// whole weight set (188 h2) + working (~25) fits in arch VGPRs.
//  * 4 lanes per hidden unit (gate-split-4, NO K-split): lane (u,gt) owns
//    the full K dot of gate gt of unit u.  L1: 84 h2, L2: 104 h2.
//  * Both layers merged in the same lanes: phase A = LSTM1 step t, barrier,
//    phase B = LSTM2 step t.  ONE __syncthreads per step (cross-iteration
//    orderings all cross that barrier; slots are parity double-buffered).
//  * Gate gather: xor1/xor2/xor3 ds_swizzles within the lane quad; all
//    lanes compute the cell redundantly as-if gt==0; lane gt==0 writes h.
//  * Biases folded via constant-1.0 elements in the LDS x-vectors.
//  * Threads 448..511 run the conv for x(t+1); 400..447 idle.

typedef _Float16 h2 __attribute__((ext_vector_type(2)));

#define BB 128
#define TT 2048
#define TP 2047
#define HH 100
#define G4 400
#define FF 64

#define S1 168   // X1 slot: [x(64); h1(100)@64; 1.0@164; 0-pad ->168]
#define S2 208   // X2 slot: [h1(100); h2(100)@100; 1.0@200; 0-pad ->208]

#define L84(X) X(0) X(1) X(2) X(3) X(4) X(5) X(6) X(7) X(8) X(9) X(10) X(11) \
 X(12) X(13) X(14) X(15) X(16) X(17) X(18) X(19) X(20) X(21) X(22) X(23) \
 X(24) X(25) X(26) X(27) X(28) X(29) X(30) X(31) X(32) X(33) X(34) X(35) \
 X(36) X(37) X(38) X(39) X(40) X(41) X(42) X(43) X(44) X(45) X(46) X(47) \
 X(48) X(49) X(50) X(51) X(52) X(53) X(54) X(55) X(56) X(57) X(58) X(59) \
 X(60) X(61) X(62) X(63) X(64) X(65) X(66) X(67) X(68) X(69) X(70) X(71) \
 X(72) X(73) X(74) X(75) X(76) X(77) X(78) X(79) X(80) X(81) X(82) X(83)
#define L104(X) L84(X) X(84) X(85) X(86) X(87) X(88) X(89) X(90) X(91) \
 X(92) X(93) X(94) X(95) X(96) X(97) X(98) X(99) X(100) X(101) X(102) X(103)

#define DP1(j) h2 wp##j;
#define DP2(j) h2 wc##j;

// L1 combined K element kk of gate column c: [x W(64); h1 U(100); b@164; 0]
static __device__ __forceinline__ float ev1(const float* __restrict__ W,
                                            const float* __restrict__ U,
                                            const float* __restrict__ Bv,
                                            int c, int kk) {
    if (kk < FF)       return W[kk * G4 + c];
    if (kk < FF + HH)  return U[(kk - FF) * G4 + c];
    if (kk == FF + HH) return Bv[c];
    return 0.0f;
}
// L2: [h1 W(100); h2 U(100); b@200; 0]
static __device__ __forceinline__ float ev2(const float* __restrict__ W,
                                            const float* __restrict__ U,
                                            const float* __restrict__ Bv,
                                            int c, int kk) {
    if (kk < HH)       return W[kk * G4 + c];
    if (kk < 2 * HH)   return U[(kk - HH) * G4 + c];
    if (kk == 2 * HH)  return Bv[c];
    return 0.0f;
}

#define LD1(j) wp##j = h2{(_Float16)ev1(w1,u1,b1,col,2*(j)), \
                          (_Float16)ev1(w1,u1,b1,col,2*(j)+1)};
#define LD2(j) wc##j = h2{(_Float16)ev2(w2,u2,b2,col,2*(j)), \
                          (_Float16)ev2(w2,u2,b2,col,2*(j)+1)};

#define B2(f) __builtin_bit_cast(h2, f)
#define FD(w, x, acc) acc = __builtin_amdgcn_fdot2(w, x, acc, false)

// one float4 (8 halves) feeds weight regs 4i..4i+3 into 4 accumulator chains
#define DA(i, a, b, c, d) { const float4 v = vb1[i]; \
  FD(wp##a, B2(v.x), z0); FD(wp##b, B2(v.y), z1); \
  FD(wp##c, B2(v.z), z2); FD(wp##d, B2(v.w), z3); }
#define DB(i, a, b, c, d) { const float4 v = vb2[i]; \
  FD(wc##a, B2(v.x), z0); FD(wc##b, B2(v.y), z1); \
  FD(wc##c, B2(v.z), z2); FD(wc##d, B2(v.w), z3); }

template <int PAT>
static __device__ __forceinline__ float swz(float z) {
    return __builtin_bit_cast(float,
        __builtin_amdgcn_ds_swizzle(__builtin_bit_cast(int, z), PAT));
}
static __device__ __forceinline__ float sig(float z) {
    return 1.0f / (1.0f + __expf(-z));
}

__global__ __launch_bounds__(512, 1)
void fused_lstm_kernel(const float* __restrict__ inp,     // [B,T]
                       const float* __restrict__ conv_w,  // [2,1,F]
                       const float* __restrict__ conv_b,  // [F]
                       const float* __restrict__ w1, const float* __restrict__ u1,
                       const float* __restrict__ b1,
                       const float* __restrict__ w2, const float* __restrict__ u2,
                       const float* __restrict__ b2,
                       const float* __restrict__ dw, const float* __restrict__ db,
                       float* __restrict__ out)           // [B,3]
{
    const int tid = threadIdx.x;
    const int b   = blockIdx.x;

    __shared__ float s_buf[TT];
    __shared__ __align__(16) _Float16 X1[2 * S1];
    __shared__ __align__(16) _Float16 X2[2 * S2];

    for (int i = tid; i < TT; i += 512) s_buf[i] = inp[(size_t)b * TT + i];
    for (int i = tid; i < 2 * S1; i += 512) X1[i] = (_Float16)0.0f;
    for (int i = tid; i < 2 * S2; i += 512) X2[i] = (_Float16)0.0f;
    __syncthreads();                                   // s_buf/zeros visible

    const bool unitlane = (tid < 400);
    const int u   = unitlane ? (tid >> 2) : 0;         // hidden unit
    const int gt  = tid & 3;                           // gate 0=i 1=f 2=g 3=o
    const int col = gt * HH + u;                       // gate column in [0,4H)

    // ---- per-lane weights in named h2 registers (84 + 104 = 188) ----
    L84(DP1)
    L104(DP2)
    if (unitlane) { L84(LD1) L104(LD2) }

    // ---- conv lanes + bias constants ----
    float cw0 = 0.f, cw1 = 0.f, cb0 = 0.f;
    const int f = tid - 448;
    if (tid >= 448) {
        cw0 = conv_w[f]; cw1 = conv_w[FF + f]; cb0 = conv_b[f];
        // x(0) into X1 slot 0
        X1[f] = (_Float16)fmaxf(fmaf(s_buf[0], cw0, fmaf(s_buf[1], cw1, cb0)), 0.f);
    }
    if (tid == 0) {                                    // bias-input constants
        X1[FF + HH] = (_Float16)1.0f; X1[S1 + FF + HH] = (_Float16)1.0f;
        X2[2 * HH]  = (_Float16)1.0f; X2[S2 + 2 * HH]  = (_Float16)1.0f;
    }
    __syncthreads();                                   // x(0), biases visible

    float c1 = 0.0f, c2 = 0.0f;
    for (int t = 0; t < TP; ++t) {
        const int cs = (t & 1), ns = cs ^ 1;
        // ================= phase A : LSTM1 step t =================
        if (unitlane) {
            float z0 = 0.f, z1 = 0.f, z2 = 0.f, z3 = 0.f;
            const float4* vb1 = (const float4*)(X1 + cs * S1);
            DA(0,0,1,2,3)     DA(1,4,5,6,7)     DA(2,8,9,10,11)
            DA(3,12,13,14,15) DA(4,16,17,18,19) DA(5,20,21,22,23)
            DA(6,24,25,26,27) DA(7,28,29,30,31) DA(8,32,33,34,35)
            DA(9,36,37,38,39) DA(10,40,41,42,43) DA(11,44,45,46,47)
            DA(12,48,49,50,51) DA(13,52,53,54,55) DA(14,56,57,58,59)
            DA(15,60,61,62,63) DA(16,64,65,66,67) DA(17,68,69,70,71)
            DA(18,72,73,74,75) DA(19,76,77,78,79) DA(20,80,81,82,83)
            float z = (z0 + z1) + (z2 + z3);           // full dot of gate gt
            const float a = (gt == 2) ? fmaxf(z, 0.f) : sig(z);
            const float a1 = swz<0x041F>(a);           // gate gt^1
            const float a2 = swz<0x081F>(a);           // gate gt^2
            const float a3 = swz<0x0C1F>(a);           // gate gt^3
            // valid in gt==0 lanes: (a,a1,a2,a3) = (i,f,g,o)
            c1 = fmaf(a1, c1, a * a2);
            const float h = a3 * fmaxf(c1, 0.f);
            if (gt == 0) {
                const _Float16 hq = (_Float16)h;
                X1[ns * S1 + FF + u] = hq;             // h1(t) for LSTM1(t+1)
                X2[cs * S2 + u]      = hq;             // h1(t) for LSTM2 phase B
            }
        } else if (tid >= 448 && t + 1 < TP) {         // conv x(t+1) -> next slot
            X1[ns * S1 + f] = (_Float16)fmaxf(
                fmaf(s_buf[t + 1], cw0, fmaf(s_buf[t + 2], cw1, cb0)), 0.f);
        }
        __syncthreads();                               // the ONE barrier per step
        // ================= phase B : LSTM2 step t =================
        if (unitlane) {
            float z0 = 0.f, z1 = 0.f, z2 = 0.f, z3 = 0.f;
            const float4* vb2 = (const float4*)(X2 + cs * S2);
            DB(0,0,1,2,3)     DB(1,4,5,6,7)     DB(2,8,9,10,11)
            DB(3,12,13,14,15) DB(4,16,17,18,19) DB(5,20,21,22,23)
            DB(6,24,25,26,27) DB(7,28,29,30,31) DB(8,32,33,34,35)
            DB(9,36,37,38,39) DB(10,40,41,42,43) DB(11,44,45,46,47)
            DB(12,48,49,50,51) DB(13,52,53,54,55) DB(14,56,57,58,59)
            DB(15,60,61,62,63) DB(16,64,65,66,67) DB(17,68,69,70,71)
            DB(18,72,73,74,75) DB(19,76,77,78,79) DB(20,80,81,82,83)
            DB(21,84,85,86,87) DB(22,88,89,90,91) DB(23,92,93,94,95)
            DB(24,96,97,98,99) DB(25,100,101,102,103)
            float z = (z0 + z1) + (z2 + z3);
            const float a = (gt == 2) ? fmaxf(z, 0.f) : sig(z);
            const float a1 = swz<0x041F>(a);
            const float a2 = swz<0x081F>(a);
            const float a3 = swz<0x0C1F>(a);
            c2 = fmaf(a1, c2, a * a2);
            const float h = a3 * fmaxf(c2, 0.f);
            if (gt == 0)
                X2[ns * S2 + HH + u] = (_Float16)h;    // h2(t)
        }
        // no barrier here: B(t) writes vs B(t+1)/A(t+1) reads are ordered by
        // the barrier inside iteration t+1; concurrent regions are disjoint.
    }
    __syncthreads();

    // final h2(TP-1) lives in X2 slot ns(TP-1)=1, h2-part
    if (tid == 0) {
        float l[3];
#pragma unroll
        for (int a = 0; a < 3; ++a) {
            float acc = db[a];
            for (int j = 0; j < HH; ++j)
                acc = fmaf((float)X2[S2 + HH + j], dw[j * 3 + a], acc);
            l[a] = acc;
        }
        const float m = fmaxf(l[0], fmaxf(l[1], l[2]));
        const float e0 = __expf(l[0] - m), e1 = __expf(l[1] - m), e2 = __expf(l[2] - m);
        const float inv = 1.0f / (e0 + e1 + e2);
        out[b * 3 + 0] = e0 * inv;
        out[b * 3 + 1] = e1 * inv;
        out[b * 3 + 2] = e2 * inv;
    }
}

// ---------------- launch ----------------------------------------------------
extern "C" void kernel_launch(void* const* d_in, const int* in_sizes, int n_in,
                              void* d_out, int out_size, void* d_ws, size_t ws_size,
                              hipStream_t stream) {
    const float* s      = (const float*)d_in[0];
    const float* conv_w = (const float*)d_in[1];
    const float* conv_b = (const float*)d_in[2];
    const float* w1     = (const float*)d_in[3];
    const float* u1     = (const float*)d_in[4];
    const float* b1     = (const float*)d_in[5];
    const float* w2     = (const float*)d_in[6];
    const float* u2     = (const float*)d_in[7];
    const float* b2     = (const float*)d_in[8];
    const float* dw     = (const float*)d_in[9];
    const float* db     = (const float*)d_in[10];

    fused_lstm_kernel<<<BB, 512, 0, stream>>>(
        s, conv_w, conv_b, w1, u1, b1, w2, u2, b2, dw, db, (float*)d_out);
}